// Round 4
// baseline (564.707 us; speedup 1.0000x reference)
//
#include <hip/hip_runtime.h>
#include <hip/hip_bf16.h>

#define BTOT 16384
#define F 26
#define V 100000
#define D 32
#define K0 832   // F*D
#define N0 128
#define N1 64
#define N2 32
#define RT 16    // rows per block
#define NT 256
#define LN_EPS 1e-5f

typedef float f32x4 __attribute__((ext_vector_type(4)));  // native vec: ok for nontemporal builtins

// Dataflow: wave w owns rows 4w..4w+3 end-to-end after the gather barrier
// (GEMM0 groups g=2w,2w+1 -> rows 4w..4w+3; GEMM1/2 groups 4w..4w+3).
// The inner barriers are therefore logically wave-local; they are kept as
// __syncthreads() for the first validated run (cost <1%), to be relaxed
// to wave fences once a passing baseline exists.

__global__ __launch_bounds__(NT, 2) void deepfm_fused(
    const int* __restrict__ fidx,
    const float* __restrict__ emb,
    const float* __restrict__ bias,
    const float* __restrict__ W0, const float* __restrict__ b0,
    const float* __restrict__ g0, const float* __restrict__ be0,
    const float* __restrict__ W1, const float* __restrict__ b1,
    const float* __restrict__ g1, const float* __restrict__ be1,
    const float* __restrict__ W2, const float* __restrict__ b2,
    const float* __restrict__ g2, const float* __restrict__ be2,
    const float* __restrict__ Wout, const float* __restrict__ bout,
    float* __restrict__ out, float* __restrict__ embeds_out)
{
    __shared__ int   s_idx[RT * F];
    __shared__ float xs[RT][K0];     // gathered x tile (row-major; stride 832 floats -> 2-way LDS alias = free)
    __shared__ float hs[RT][132];    // h1 (128 + 4 pad)
    __shared__ float hs2[RT][68];    // h2 (64 + 4 pad)

    const int tid  = threadIdx.x;
    const int row0 = blockIdx.x * RT;
    const int grp_row = tid >> 4;    // 16-lane group -> one row (FM / GEMM1 / GEMM2)
    const int lane16  = tid & 15;

    // ---- load indices for this row tile (416 ints, coalesced) ----
    for (int i = tid; i < RT * F; i += NT) s_idx[i] = fidx[row0 * F + i];
    __syncthreads();

    // ---- hoisted first-order bias gather (overlaps with embedding gather) ----
    float bsum;
    {
        const int f0 = lane16, f1 = lane16 + 16;
        bsum = bias[(size_t)f0 * V + s_idx[grp_row * F + f0]];
        if (f1 < F) bsum += bias[(size_t)f1 * V + s_idx[grp_row * F + f1]];
    }

    // ---- gather embeddings -> xs + embeds output (16B per thread-task) ----
    for (int i = tid; i < RT * F * 8; i += NT) {
        const int pair = i >> 3, part = i & 7;
        const int row = pair / F, f = pair - row * F;
        const int idx = s_idx[pair];
        const f32x4 v = __builtin_nontemporal_load(
            reinterpret_cast<const f32x4*>(emb + ((size_t)f * V + idx) * D + part * 4));
        *reinterpret_cast<f32x4*>(&xs[row][f * D + part * 4]) = v;
        __builtin_nontemporal_store(v,
            reinterpret_cast<f32x4*>(embeds_out + ((size_t)(row0 + row) * F + f) * D + part * 4));
    }
    __syncthreads();

    // ---- FM second order; row handled by its 16-lane group, 2 dims per lane ----
    float fm_val;
    {
        const int d0 = lane16 * 2;
        float s0 = 0.f, s1 = 0.f, q0 = 0.f, q1 = 0.f;
        #pragma unroll
        for (int f = 0; f < F; f++) {
            const float2 e = *reinterpret_cast<const float2*>(&xs[grp_row][f * D + d0]);
            s0 += e.x; q0 += e.x * e.x;
            s1 += e.y; q1 += e.y * e.y;
        }
        float p = 0.5f * ((s0 * s0 - q0) + (s1 * s1 - q1)) + bsum;
        #pragma unroll
        for (int o = 8; o > 0; o >>= 1) p += __shfl_xor(p, o, 16);
        fm_val = p;   // valid on all 16 lanes of the group
    }

    // ---- GEMM0: [16 x 832] @ [832 x 128], thread = 2 rows x 4 cols ----
    const int c4 = (tid & 31) * 4;          // col 0..124
    const int r0 = (tid >> 5) * 2;          // rows {2g, 2g+1}
    float acc[2][4] = {};
    for (int k = 0; k < K0; k += 4) {
        const float4 xa = *reinterpret_cast<const float4*>(&xs[r0][k]);
        const float4 xb = *reinterpret_cast<const float4*>(&xs[r0 + 1][k]);
        const float* wp = W0 + (size_t)k * N0 + c4;
        #pragma unroll
        for (int kk = 0; kk < 4; kk++) {
            const float4 w = *reinterpret_cast<const float4*>(wp + kk * N0);
            const float a0 = (&xa.x)[kk], a1 = (&xb.x)[kk];
            acc[0][0] += a0 * w.x; acc[0][1] += a0 * w.y; acc[0][2] += a0 * w.z; acc[0][3] += a0 * w.w;
            acc[1][0] += a1 * w.x; acc[1][1] += a1 * w.y; acc[1][2] += a1 * w.z; acc[1][3] += a1 * w.w;
        }
    }
    {   // bias + relu + LayerNorm(128); each row owned by 32 contiguous lanes
        const float4 bb  = *reinterpret_cast<const float4*>(b0 + c4);
        const float4 gg  = *reinterpret_cast<const float4*>(g0 + c4);
        const float4 beb = *reinterpret_cast<const float4*>(be0 + c4);
        float h[2][4];
        float sum[2], sq[2];
        #pragma unroll
        for (int r = 0; r < 2; r++) {
            h[r][0] = fmaxf(acc[r][0] + bb.x, 0.f);
            h[r][1] = fmaxf(acc[r][1] + bb.y, 0.f);
            h[r][2] = fmaxf(acc[r][2] + bb.z, 0.f);
            h[r][3] = fmaxf(acc[r][3] + bb.w, 0.f);
            sum[r] = h[r][0] + h[r][1] + h[r][2] + h[r][3];
            sq[r]  = h[r][0]*h[r][0] + h[r][1]*h[r][1] + h[r][2]*h[r][2] + h[r][3]*h[r][3];
        }
        #pragma unroll
        for (int o = 16; o > 0; o >>= 1) {
            sum[0] += __shfl_xor(sum[0], o, 32);
            sq[0]  += __shfl_xor(sq[0],  o, 32);
            sum[1] += __shfl_xor(sum[1], o, 32);
            sq[1]  += __shfl_xor(sq[1],  o, 32);
        }
        #pragma unroll
        for (int r = 0; r < 2; r++) {
            const float mu = sum[r] * (1.f / N0);
            const float var = sq[r] * (1.f / N0) - mu * mu;
            const float rstd = rsqrtf(var + LN_EPS);
            float4 y;
            y.x = gg.x * (h[r][0] - mu) * rstd + beb.x;
            y.y = gg.y * (h[r][1] - mu) * rstd + beb.y;
            y.z = gg.z * (h[r][2] - mu) * rstd + beb.z;
            y.w = gg.w * (h[r][3] - mu) * rstd + beb.w;
            *reinterpret_cast<float4*>(&hs[r0 + r][c4]) = y;
        }
    }
    __syncthreads();

    // ---- GEMM1: [16 x 128] @ [128 x 64], thread = 1 row x 4 cols ----
    const int c1 = lane16 * 4;
    float a1[4] = {};
    #pragma unroll 4
    for (int k = 0; k < N0; k += 4) {
        const float4 hh = *reinterpret_cast<const float4*>(&hs[grp_row][k]);
        const float* wp = W1 + k * N1 + c1;
        #pragma unroll
        for (int kk = 0; kk < 4; kk++) {
            const float4 w = *reinterpret_cast<const float4*>(wp + kk * N1);
            const float a = (&hh.x)[kk];
            a1[0] += a * w.x; a1[1] += a * w.y; a1[2] += a * w.z; a1[3] += a * w.w;
        }
    }
    {   // bias + relu + LN(64); row owned by its 16-lane group
        const float4 bb  = *reinterpret_cast<const float4*>(b1 + c1);
        const float4 gg  = *reinterpret_cast<const float4*>(g1 + c1);
        const float4 beb = *reinterpret_cast<const float4*>(be1 + c1);
        float h0 = fmaxf(a1[0] + bb.x, 0.f), h1v = fmaxf(a1[1] + bb.y, 0.f);
        float h2v = fmaxf(a1[2] + bb.z, 0.f), h3 = fmaxf(a1[3] + bb.w, 0.f);
        float sum = h0 + h1v + h2v + h3;
        float sq  = h0*h0 + h1v*h1v + h2v*h2v + h3*h3;
        #pragma unroll
        for (int o = 8; o > 0; o >>= 1) { sum += __shfl_xor(sum, o, 16); sq += __shfl_xor(sq, o, 16); }
        const float mu = sum * (1.f / N1);
        const float var = sq * (1.f / N1) - mu * mu;
        const float rstd = rsqrtf(var + LN_EPS);
        float4 y;
        y.x = gg.x * (h0 - mu) * rstd + beb.x;
        y.y = gg.y * (h1v - mu) * rstd + beb.y;
        y.z = gg.z * (h2v - mu) * rstd + beb.z;
        y.w = gg.w * (h3 - mu) * rstd + beb.w;
        *reinterpret_cast<float4*>(&hs2[grp_row][c1]) = y;
    }
    __syncthreads();

    // ---- GEMM2: [16 x 64] @ [64 x 32], thread = 1 row x 2 cols ----
    const int c2 = lane16 * 2;
    float a2[2] = {};
    #pragma unroll 4
    for (int k = 0; k < N1; k += 4) {
        const float4 hh = *reinterpret_cast<const float4*>(&hs2[grp_row][k]);
        #pragma unroll
        for (int kk = 0; kk < 4; kk++) {
            const float2 w = *reinterpret_cast<const float2*>(W2 + (k + kk) * N2 + c2);
            const float a = (&hh.x)[kk];
            a2[0] += a * w.x; a2[1] += a * w.y;
        }
    }
    {   // bias + relu + LN(32) + output head
        const float2 bb  = *reinterpret_cast<const float2*>(b2 + c2);
        const float2 gg  = *reinterpret_cast<const float2*>(g2 + c2);
        const float2 beb = *reinterpret_cast<const float2*>(be2 + c2);
        const float h0 = fmaxf(a2[0] + bb.x, 0.f);
        const float h1v = fmaxf(a2[1] + bb.y, 0.f);
        float sum = h0 + h1v, sq = h0*h0 + h1v*h1v;
        #pragma unroll
        for (int o = 8; o > 0; o >>= 1) { sum += __shfl_xor(sum, o, 16); sq += __shfl_xor(sq, o, 16); }
        const float mu = sum * (1.f / N2);
        const float var = sq * (1.f / N2) - mu * mu;
        const float rstd = rsqrtf(var + LN_EPS);
        const float y0 = gg.x * (h0 - mu) * rstd + beb.x;
        const float y1 = gg.y * (h1v - mu) * rstd + beb.y;
        const float2 wo = *reinterpret_cast<const float2*>(Wout + c2);
        float p = y0 * wo.x + y1 * wo.y;
        #pragma unroll
        for (int o = 8; o > 0; o >>= 1) p += __shfl_xor(p, o, 16);
        if (lane16 == 0) {
            const float z = p + bout[0] + fm_val;
            out[row0 + grp_row] = 1.f / (1.f + expf(-z));
        }
    }
}

extern "C" void kernel_launch(void* const* d_in, const int* in_sizes, int n_in,
                              void* d_out, int out_size, void* d_ws, size_t ws_size,
                              hipStream_t stream) {
    const int*   fidx = (const int*)  d_in[0];
    const float* emb  = (const float*)d_in[1];
    const float* bias = (const float*)d_in[2];
    const float* W0   = (const float*)d_in[3];
    const float* b0   = (const float*)d_in[4];
    const float* g0   = (const float*)d_in[5];
    const float* be0  = (const float*)d_in[6];
    const float* W1   = (const float*)d_in[7];
    const float* b1   = (const float*)d_in[8];
    const float* g1   = (const float*)d_in[9];
    const float* be1  = (const float*)d_in[10];
    const float* W2   = (const float*)d_in[11];
    const float* b2   = (const float*)d_in[12];
    const float* g2   = (const float*)d_in[13];
    const float* be2  = (const float*)d_in[14];
    const float* Wout = (const float*)d_in[15];
    const float* bout = (const float*)d_in[16];

    float* out        = (float*)d_out;            // [B] sigmoid outputs
    float* embeds_out = (float*)d_out + BTOT;     // [B, F, D]

    dim3 grid(BTOT / RT), block(NT);
    deepfm_fused<<<grid, block, 0, stream>>>(
        fidx, emb, bias, W0, b0, g0, be0, W1, b1, g1, be1,
        W2, b2, g2, be2, Wout, bout, out, embeds_out);
}